// Round 3
// baseline (615.733 us; speedup 1.0000x reference)
//
#include <hip/hip_runtime.h>

#define NFACE 400000
#define NVERT 200000
#define CIN 64
#define COUT 128
#define KF 27
#define CAP 64            // max faces per vertex tracked (Poisson(6) tail ~1e-40)
#define BN_EPS 1e-5f

// ---------------- Kernel 1: build per-vertex face adjacency --------------
__global__ __launch_bounds__(256) void fill_adj_k(
    const int* __restrict__ face,   // [NF,3]
    int* __restrict__ counts,       // [NV]
    int* __restrict__ adj)          // [NV,CAP]
{
    int f = blockIdx.x * 256 + threadIdx.x;
    if (f >= NFACE) return;
    int v0 = face[f * 3 + 0];
    int v1 = face[f * 3 + 1];
    int v2 = face[f * 3 + 2];
    int s0 = atomicAdd(&counts[v0], 1);
    if (s0 < CAP) adj[v0 * CAP + s0] = f;
    int s1 = atomicAdd(&counts[v1], 1);
    if (s1 < CAP) adj[v1 * CAP + s1] = f;
    int s2 = atomicAdd(&counts[v2], 1);
    if (s2 < CAP) adj[v2 * CAP + s2] = f;
}

// ---------------- Kernel 2: per-vertex gather (pull) ---------------------
// One wave per source vertex; lane = channel. Recomputes the 27-tap spatial
// mix per adjacent face (cheap) instead of scattering with f32 atomics.
__global__ __launch_bounds__(256) void gather_k(
    const float* __restrict__ inputs,   // [NF,64]
    const float* __restrict__ filt,     // [NF,27]
    const int* __restrict__ counts,     // [NV]
    const int* __restrict__ adj,        // [NV,CAP]
    const float* __restrict__ sw,       // [27,64]
    float* __restrict__ agg)            // [NV,64]
{
    __shared__ float swl[KF * 64];
    for (int i = threadIdx.x; i < KF * 64; i += 256) swl[i] = sw[i];
    __syncthreads();

    const int lane = threadIdx.x & 63;
    const int src  = blockIdx.x * 4 + (threadIdx.x >> 6);   // wave id = vertex
    int n = counts[src];
    n = n > CAP ? CAP : n;
    int adjv = (lane < n) ? adj[src * CAP + lane] : 0;

    float acc = 0.f;
    for (int j = 0; j < n; ++j) {
        int f = __shfl(adjv, j);
        float fcv = 0.f;
        if (lane < KF) fcv = filt[f * KF + lane];
        float w = 0.f;
#pragma unroll
        for (int k = 0; k < KF; ++k)
            w += __shfl(fcv, k) * swl[k * 64 + lane];
        acc += inputs[f * 64 + lane] * w;
    }
    agg[src * 64 + lane] = acc;
}

// ---------------- Kernel 3: gather + pointwise conv + bias + ReLU + stats
#define BV 32   // vertices per block
__global__ __launch_bounds__(256) void pconv_k(
    const float* __restrict__ agg,       // [NV,64]
    const int* __restrict__ nf_count,    // [NV]
    const int* __restrict__ vt_map,      // [NV] (JAX x64-disabled -> int32)
    const float* __restrict__ dw,        // [64,128]
    const float* __restrict__ bias,      // [128]
    float* __restrict__ out,             // [NV,128]
    float* __restrict__ stats)           // [8][256]
{
    __shared__ float W[64 * 128];   // 32 KB
    __shared__ float A[BV][64];     // 8 KB
    for (int i = threadIdx.x; i < 64 * 128; i += 256) W[i] = dw[i];

    const int vbase = blockIdx.x * BV;
    for (int i = threadIdx.x; i < BV * 64; i += 256) {
        int vv = vbase + (i >> 6);
        int src = vt_map[vv];
        float denom = (float)max(nf_count[src], 1);
        A[i >> 6][i & 63] = agg[(size_t)src * 64 + (i & 63)] / denom;
    }
    __syncthreads();

    const int c    = threadIdx.x & 127;
    const int half = threadIdx.x >> 7;
    float s = 0.f, s2 = 0.f;
    for (int vi = half * (BV / 2); vi < (half + 1) * (BV / 2); ++vi) {
        const float4* A4 = reinterpret_cast<const float4*>(&A[vi][0]);
        float acc = bias[c];
#pragma unroll
        for (int k4 = 0; k4 < 16; ++k4) {
            float4 a = A4[k4];
            acc += a.x * W[(k4 * 4 + 0) * 128 + c];
            acc += a.y * W[(k4 * 4 + 1) * 128 + c];
            acc += a.z * W[(k4 * 4 + 2) * 128 + c];
            acc += a.w * W[(k4 * 4 + 3) * 128 + c];
        }
        acc = fmaxf(acc, 0.f);
        out[(size_t)(vbase + vi) * 128 + c] = acc;
        s  += acc;
        s2 += acc * acc;
    }
    float* st = stats + (blockIdx.x & 7) * 256;
    atomicAdd(&st[c], s);
    atomicAdd(&st[128 + c], s2);
}

// ---------------- Kernel 4: BatchNorm finalize (in place on d_out) --------
__global__ __launch_bounds__(256) void bn_k(
    float* __restrict__ out,
    const float* __restrict__ stats,
    const float* __restrict__ gamma,
    const float* __restrict__ beta)
{
    __shared__ float sc[128], sh[128];
    if (threadIdx.x < 128) {
        int c = threadIdx.x;
        float s = 0.f, s2 = 0.f;
#pragma unroll
        for (int r = 0; r < 8; ++r) {
            s  += stats[r * 256 + c];
            s2 += stats[r * 256 + 128 + c];
        }
        float mean = s / (float)NVERT;
        float var  = s2 / (float)NVERT - mean * mean;
        float inv  = rsqrtf(var + BN_EPS) * gamma[c];
        sc[c] = inv;
        sh[c] = beta[c] - mean * inv;
    }
    __syncthreads();

    float4* o4 = reinterpret_cast<float4*>(out);
    size_t total4 = (size_t)NVERT * COUT / 4;
    for (size_t i = (size_t)blockIdx.x * 256 + threadIdx.x; i < total4;
         i += (size_t)gridDim.x * 256) {
        int c0 = (int)((i * 4) & 127);
        float4 v = o4[i];
        v.x = v.x * sc[c0 + 0] + sh[c0 + 0];
        v.y = v.y * sc[c0 + 1] + sh[c0 + 1];
        v.z = v.z * sc[c0 + 2] + sh[c0 + 2];
        v.w = v.w * sc[c0 + 3] + sh[c0 + 3];
        o4[i] = v;
    }
}

extern "C" void kernel_launch(void* const* d_in, const int* in_sizes, int n_in,
                              void* d_out, int out_size, void* d_ws, size_t ws_size,
                              hipStream_t stream) {
    const float* inputs   = (const float*)d_in[0];
    const float* filt     = (const float*)d_in[1];
    const int*   face     = (const int*)d_in[2];
    const int*   nf_count = (const int*)d_in[3];
    const int*   vt_map   = (const int*)d_in[4];
    const float* sw       = (const float*)d_in[5];
    const float* dw       = (const float*)d_in[6];
    const float* bias     = (const float*)d_in[7];
    const float* gamma    = (const float*)d_in[8];
    const float* beta     = (const float*)d_in[9];
    float* out = (float*)d_out;

    // ws layout: [stats 8KB][agg 51.2MB]  (proven-fitting footprint)
    float* stats = (float*)d_ws;
    float* agg   = (float*)((char*)d_ws + 8192);

    // adjacency staged INSIDE d_out (fully consumed by gather_k before
    // pconv_k overwrites d_out; same-stream kernel ordering guarantees this)
    int* adj    = (int*)d_out;                                   // [NV,CAP] 51.2 MB
    int* counts = (int*)((char*)d_out + (size_t)NVERT * CAP * 4); // [NV] 0.8 MB

    hipMemsetAsync(stats, 0, 8192, stream);
    hipMemsetAsync(counts, 0, (size_t)NVERT * sizeof(int), stream);

    fill_adj_k<<<(NFACE + 255) / 256, 256, 0, stream>>>(face, counts, adj);
    gather_k<<<NVERT / 4, 256, 0, stream>>>(inputs, filt, counts, adj, sw, agg);
    pconv_k<<<NVERT / BV, 256, 0, stream>>>(agg, nf_count, vt_map, dw, bias, out, stats);
    bn_k<<<2048, 256, 0, stream>>>(out, stats, gamma, beta);
}

// Round 4
// 431.932 us; speedup vs baseline: 1.4255x; 1.4255x over previous
//
#include <hip/hip_runtime.h>
#include <hip/hip_bf16.h>

#define NFACE 400000
#define NVERT 200000
#define CIN 64
#define COUT 128
#define KF 27
#define CAP 32            // max faces/vertex (Poisson(6), max over 200k ~21)
#define BN_EPS 1e-5f

// ---------------- Kernel 1: streaming per-face contrib (bf16) -------------
__global__ __launch_bounds__(256) void contrib_k(
    const float* __restrict__ inputs,   // [NF,64]
    const float* __restrict__ filt,     // [NF,27]
    const float* __restrict__ sw,       // [27,64]
    __hip_bfloat16* __restrict__ contrib) // [NF,64]
{
    __shared__ float swl[KF * 64];
    for (int i = threadIdx.x; i < KF * 64; i += 256) swl[i] = sw[i];
    __syncthreads();

    const int lane = threadIdx.x & 63;
    const int wid  = threadIdx.x >> 6;
    int f = blockIdx.x * 16 + wid;
#pragma unroll
    for (int it = 0; it < 4; ++it, f += 4) {
        float fcv = 0.f;
        if (lane < KF) fcv = filt[f * KF + lane];
        float w = 0.f;
#pragma unroll
        for (int k = 0; k < KF; ++k)
            w += __shfl(fcv, k) * swl[k * 64 + lane];
        float v = inputs[f * 64 + lane] * w;
        contrib[(size_t)f * 64 + lane] = __float2bfloat16(v);
    }
}

// ---------------- Kernel 2: build per-vertex face adjacency ---------------
__global__ __launch_bounds__(256) void fill_adj_k(
    const int* __restrict__ face,   // [NF,3]
    int* __restrict__ counts,       // [NV]
    int* __restrict__ adj)          // [NV,CAP]
{
    int f = blockIdx.x * 256 + threadIdx.x;
    if (f >= NFACE) return;
    int v0 = face[f * 3 + 0];
    int v1 = face[f * 3 + 1];
    int v2 = face[f * 3 + 2];
    int s0 = atomicAdd(&counts[v0], 1);
    if (s0 < CAP) adj[v0 * CAP + s0] = f;
    int s1 = atomicAdd(&counts[v1], 1);
    if (s1 < CAP) adj[v1 * CAP + s1] = f;
    int s2 = atomicAdd(&counts[v2], 1);
    if (s2 < CAP) adj[v2 * CAP + s2] = f;
}

// ---------------- Kernel 3: per-vertex gather with MLP --------------------
__global__ __launch_bounds__(256) void gather2_k(
    const __hip_bfloat16* __restrict__ contrib, // [NF,64]
    const int* __restrict__ counts,             // [NV]
    const int* __restrict__ adj,                // [NV,CAP]
    const int* __restrict__ nf_count,           // [NV]
    float* __restrict__ agg)                    // [NV,64] (already /denom)
{
    const int lane = threadIdx.x & 63;
    const int src  = blockIdx.x * 4 + (threadIdx.x >> 6);
    int n = counts[src];
    n = n > CAP ? CAP : n;
    int adjv = (lane < n) ? adj[src * CAP + lane] : 0;

    float acc = 0.f;
    int j = 0;
    for (; j + 4 <= n; j += 4) {
        int f0 = __shfl(adjv, j + 0);
        int f1 = __shfl(adjv, j + 1);
        int f2 = __shfl(adjv, j + 2);
        int f3 = __shfl(adjv, j + 3);
        // 4 independent 128B row loads -> MLP
        float a0 = __bfloat162float(contrib[(size_t)f0 * 64 + lane]);
        float a1 = __bfloat162float(contrib[(size_t)f1 * 64 + lane]);
        float a2 = __bfloat162float(contrib[(size_t)f2 * 64 + lane]);
        float a3 = __bfloat162float(contrib[(size_t)f3 * 64 + lane]);
        acc += (a0 + a1) + (a2 + a3);
    }
    for (; j < n; ++j) {
        int f = __shfl(adjv, j);
        acc += __bfloat162float(contrib[(size_t)f * 64 + lane]);
    }
    float denom = (float)max(nf_count[src], 1);
    agg[(size_t)src * 64 + lane] = acc / denom;
}

// ---------------- Kernel 4: pointwise conv + bias + ReLU + BN stats -------
#define BV 32   // vertices per block
__global__ __launch_bounds__(256) void pconv_k(
    const float* __restrict__ agg,       // [NV,64] (pre-divided)
    const int* __restrict__ vt_map,      // [NV] (int32)
    const float* __restrict__ dw,        // [64,128]
    const float* __restrict__ bias,      // [128]
    float* __restrict__ out,             // [NV,128]
    float* __restrict__ stats)           // [8][256]
{
    __shared__ float W[64 * 128];   // 32 KB
    __shared__ float A[BV][64];     // 8 KB
    for (int i = threadIdx.x; i < 64 * 128; i += 256) W[i] = dw[i];

    const int vbase = blockIdx.x * BV;
    for (int i = threadIdx.x; i < BV * 64; i += 256) {
        int vv = vbase + (i >> 6);
        int src = vt_map[vv];
        A[i >> 6][i & 63] = agg[(size_t)src * 64 + (i & 63)];
    }
    __syncthreads();

    const int c    = threadIdx.x & 127;
    const int half = threadIdx.x >> 7;
    float s = 0.f, s2 = 0.f;
    for (int vi = half * (BV / 2); vi < (half + 1) * (BV / 2); ++vi) {
        const float4* A4 = reinterpret_cast<const float4*>(&A[vi][0]);
        float acc = bias[c];
#pragma unroll
        for (int k4 = 0; k4 < 16; ++k4) {
            float4 a = A4[k4];
            acc += a.x * W[(k4 * 4 + 0) * 128 + c];
            acc += a.y * W[(k4 * 4 + 1) * 128 + c];
            acc += a.z * W[(k4 * 4 + 2) * 128 + c];
            acc += a.w * W[(k4 * 4 + 3) * 128 + c];
        }
        acc = fmaxf(acc, 0.f);
        out[(size_t)(vbase + vi) * 128 + c] = acc;
        s  += acc;
        s2 += acc * acc;
    }
    float* st = stats + (blockIdx.x & 7) * 256;
    atomicAdd(&st[c], s);
    atomicAdd(&st[128 + c], s2);
}

// ---------------- Kernel 5: BatchNorm finalize (in place on d_out) --------
__global__ __launch_bounds__(256) void bn_k(
    float* __restrict__ out,
    const float* __restrict__ stats,
    const float* __restrict__ gamma,
    const float* __restrict__ beta)
{
    __shared__ float sc[128], sh[128];
    if (threadIdx.x < 128) {
        int c = threadIdx.x;
        float s = 0.f, s2 = 0.f;
#pragma unroll
        for (int r = 0; r < 8; ++r) {
            s  += stats[r * 256 + c];
            s2 += stats[r * 256 + 128 + c];
        }
        float mean = s / (float)NVERT;
        float var  = s2 / (float)NVERT - mean * mean;
        float inv  = rsqrtf(var + BN_EPS) * gamma[c];
        sc[c] = inv;
        sh[c] = beta[c] - mean * inv;
    }
    __syncthreads();

    float4* o4 = reinterpret_cast<float4*>(out);
    size_t total4 = (size_t)NVERT * COUT / 4;
    for (size_t i = (size_t)blockIdx.x * 256 + threadIdx.x; i < total4;
         i += (size_t)gridDim.x * 256) {
        int c0 = (int)((i * 4) & 127);
        float4 v = o4[i];
        v.x = v.x * sc[c0 + 0] + sh[c0 + 0];
        v.y = v.y * sc[c0 + 1] + sh[c0 + 1];
        v.z = v.z * sc[c0 + 2] + sh[c0 + 2];
        v.w = v.w * sc[c0 + 3] + sh[c0 + 3];
        o4[i] = v;
    }
}

extern "C" void kernel_launch(void* const* d_in, const int* in_sizes, int n_in,
                              void* d_out, int out_size, void* d_ws, size_t ws_size,
                              hipStream_t stream) {
    const float* inputs   = (const float*)d_in[0];
    const float* filt     = (const float*)d_in[1];
    const int*   face     = (const int*)d_in[2];
    const int*   nf_count = (const int*)d_in[3];
    const int*   vt_map   = (const int*)d_in[4];
    const float* sw       = (const float*)d_in[5];
    const float* dw       = (const float*)d_in[6];
    const float* bias     = (const float*)d_in[7];
    const float* gamma    = (const float*)d_in[8];
    const float* beta     = (const float*)d_in[9];
    float* out = (float*)d_out;

    // ws: [stats 8KB][agg 51.2MB]   (proven footprint)
    float* stats = (float*)d_ws;
    float* agg   = (float*)((char*)d_ws + 8192);

    // staged inside d_out (dead before pconv_k overwrites it):
    //   [contrib bf16 51.2MB][adj 25.6MB][counts 0.8MB] = 77.6MB < 102.4MB
    __hip_bfloat16* contrib = (__hip_bfloat16*)d_out;
    int* adj    = (int*)((char*)d_out + (size_t)NFACE * CIN * 2);
    int* counts = (int*)((char*)adj + (size_t)NVERT * CAP * 4);

    hipMemsetAsync(stats, 0, 8192, stream);
    hipMemsetAsync(counts, 0, (size_t)NVERT * sizeof(int), stream);

    contrib_k<<<NFACE / 16, 256, 0, stream>>>(inputs, filt, sw, contrib);
    fill_adj_k<<<(NFACE + 255) / 256, 256, 0, stream>>>(face, counts, adj);
    gather2_k<<<NVERT / 4, 256, 0, stream>>>(contrib, counts, adj, nf_count, agg);
    pconv_k<<<NVERT / BV, 256, 0, stream>>>(agg, vt_map, dw, bias, out, stats);
    bn_k<<<2048, 256, 0, stream>>>(out, stats, gamma, beta);
}

// Round 5
// 314.995 us; speedup vs baseline: 1.9547x; 1.3712x over previous
//
#include <hip/hip_runtime.h>
#include <hip/hip_bf16.h>

#define NFACE 400000
#define NVERT 200000
#define CIN 64
#define COUT 128
#define KF 27
#define CAP 32            // max faces/vertex (Poisson(6), max over 200k ~21)
#define BN_EPS 1e-5f

// ---- Kernel 1: per-face contrib (bf16) + adjacency build (fused) ---------
// One wave per face (4 faces per wave via it-loop). lane = channel.
// filt row read via wave-uniform SGPR loads; sw column held in VGPRs.
__global__ __launch_bounds__(256) void contrib_adj_k(
    const float* __restrict__ inputs,   // [NF,64]
    const float* __restrict__ filt,     // [NF,27]
    const int*   __restrict__ face,     // [NF,3]
    const float* __restrict__ sw,       // [27,64]
    __hip_bfloat16* __restrict__ contrib, // [NF,64]
    int* __restrict__ counts,           // [NV]
    int* __restrict__ adj)              // [NV,CAP]
{
    const int lane = threadIdx.x & 63;
    const int wid  = threadIdx.x >> 6;

    // spatial weights column for this lane: 27 VGPRs
    float swv[KF];
#pragma unroll
    for (int k = 0; k < KF; ++k) swv[k] = sw[k * 64 + lane];

    int f = blockIdx.x * 16 + wid;
#pragma unroll
    for (int it = 0; it < 4; ++it, f += 4) {
        // adjacency: 3 lanes do the int atomics for this face
        if (lane < 3) {
            int v = face[f * 3 + lane];
            int s = atomicAdd(&counts[v], 1);
            if (s < CAP) adj[v * CAP + s] = f;
        }
        // wave-uniform filter row -> scalar loads
        const float* frow = filt + (size_t)__builtin_amdgcn_readfirstlane(f) * KF;
        float w = 0.f;
#pragma unroll
        for (int k = 0; k < KF; ++k) w += frow[k] * swv[k];
        float v = inputs[(size_t)f * 64 + lane] * w;
        contrib[(size_t)f * 64 + lane] = __float2bfloat16(v);
    }
}

// ---- Kernel 2: per-vertex gather with MLP --------------------------------
__global__ __launch_bounds__(256) void gather2_k(
    const __hip_bfloat16* __restrict__ contrib, // [NF,64]
    const int* __restrict__ counts,             // [NV]
    const int* __restrict__ adj,                // [NV,CAP]
    const int* __restrict__ nf_count,           // [NV]
    float* __restrict__ agg)                    // [NV,64] (already /denom)
{
    const int lane = threadIdx.x & 63;
    const int src  = blockIdx.x * 4 + (threadIdx.x >> 6);
    int n = counts[src];
    n = n > CAP ? CAP : n;
    int adjv = (lane < n) ? adj[src * CAP + lane] : 0;

    float acc = 0.f;
    int j = 0;
    for (; j + 4 <= n; j += 4) {
        int f0 = __shfl(adjv, j + 0);
        int f1 = __shfl(adjv, j + 1);
        int f2 = __shfl(adjv, j + 2);
        int f3 = __shfl(adjv, j + 3);
        float a0 = __bfloat162float(contrib[(size_t)f0 * 64 + lane]);
        float a1 = __bfloat162float(contrib[(size_t)f1 * 64 + lane]);
        float a2 = __bfloat162float(contrib[(size_t)f2 * 64 + lane]);
        float a3 = __bfloat162float(contrib[(size_t)f3 * 64 + lane]);
        acc += (a0 + a1) + (a2 + a3);
    }
    for (; j < n; ++j) {
        int f = __shfl(adjv, j);
        acc += __bfloat162float(contrib[(size_t)f * 64 + lane]);
    }
    float denom = (float)max(nf_count[src], 1);
    agg[(size_t)src * 64 + lane] = acc / denom;
}

// ---- Kernel 3: pointwise conv + bias + ReLU + BN stats -------------------
#define BV 32   // vertices per block
__global__ __launch_bounds__(256) void pconv_k(
    const float* __restrict__ agg,       // [NV,64] (pre-divided)
    const int* __restrict__ vt_map,      // [NV] (int32)
    const float* __restrict__ dw,        // [64,128]
    const float* __restrict__ bias,      // [128]
    float* __restrict__ out,             // [NV,128]
    float* __restrict__ stats)           // [8][256]
{
    __shared__ float A[BV][64];     // 8 KB only
    const int c = threadIdx.x & 127;

    // weight column held in registers (64 VGPRs), coalesced global loads
    float wreg[64];
#pragma unroll
    for (int k = 0; k < 64; ++k) wreg[k] = dw[k * 128 + c];

    const int vbase = blockIdx.x * BV;
    for (int i = threadIdx.x; i < BV * 64; i += 256) {
        int vv = vbase + (i >> 6);
        int src = vt_map[vv];
        A[i >> 6][i & 63] = agg[(size_t)src * 64 + (i & 63)];
    }
    __syncthreads();

    const int half = threadIdx.x >> 7;
    float s = 0.f, s2 = 0.f;
    for (int vi = half * (BV / 2); vi < (half + 1) * (BV / 2); ++vi) {
        const float4* A4 = reinterpret_cast<const float4*>(&A[vi][0]);
        float acc = bias[c];
#pragma unroll
        for (int k4 = 0; k4 < 16; ++k4) {
            float4 a = A4[k4];   // uniform-address LDS broadcast
            acc += a.x * wreg[k4 * 4 + 0];
            acc += a.y * wreg[k4 * 4 + 1];
            acc += a.z * wreg[k4 * 4 + 2];
            acc += a.w * wreg[k4 * 4 + 3];
        }
        acc = fmaxf(acc, 0.f);
        out[(size_t)(vbase + vi) * 128 + c] = acc;
        s  += acc;
        s2 += acc * acc;
    }
    float* st = stats + (blockIdx.x & 7) * 256;
    atomicAdd(&st[c], s);
    atomicAdd(&st[128 + c], s2);
}

// ---- Kernel 4: BatchNorm finalize (in place on d_out) --------------------
__global__ __launch_bounds__(256) void bn_k(
    float* __restrict__ out,
    const float* __restrict__ stats,
    const float* __restrict__ gamma,
    const float* __restrict__ beta)
{
    __shared__ float sc[128], sh[128];
    if (threadIdx.x < 128) {
        int c = threadIdx.x;
        float s = 0.f, s2 = 0.f;
#pragma unroll
        for (int r = 0; r < 8; ++r) {
            s  += stats[r * 256 + c];
            s2 += stats[r * 256 + 128 + c];
        }
        float mean = s / (float)NVERT;
        float var  = s2 / (float)NVERT - mean * mean;
        float inv  = rsqrtf(var + BN_EPS) * gamma[c];
        sc[c] = inv;
        sh[c] = beta[c] - mean * inv;
    }
    __syncthreads();

    float4* o4 = reinterpret_cast<float4*>(out);
    size_t total4 = (size_t)NVERT * COUT / 4;
    for (size_t i = (size_t)blockIdx.x * 256 + threadIdx.x; i < total4;
         i += (size_t)gridDim.x * 256) {
        int c0 = (int)((i * 4) & 127);
        float4 v = o4[i];
        v.x = v.x * sc[c0 + 0] + sh[c0 + 0];
        v.y = v.y * sc[c0 + 1] + sh[c0 + 1];
        v.z = v.z * sc[c0 + 2] + sh[c0 + 2];
        v.w = v.w * sc[c0 + 3] + sh[c0 + 3];
        o4[i] = v;
    }
}

extern "C" void kernel_launch(void* const* d_in, const int* in_sizes, int n_in,
                              void* d_out, int out_size, void* d_ws, size_t ws_size,
                              hipStream_t stream) {
    const float* inputs   = (const float*)d_in[0];
    const float* filt     = (const float*)d_in[1];
    const int*   face     = (const int*)d_in[2];
    const int*   nf_count = (const int*)d_in[3];
    const int*   vt_map   = (const int*)d_in[4];
    const float* sw       = (const float*)d_in[5];
    const float* dw       = (const float*)d_in[6];
    const float* bias     = (const float*)d_in[7];
    const float* gamma    = (const float*)d_in[8];
    const float* beta     = (const float*)d_in[9];
    float* out = (float*)d_out;

    // ws: [stats 8KB][agg 51.2MB]
    float* stats = (float*)d_ws;
    float* agg   = (float*)((char*)d_ws + 8192);

    // staged inside d_out (dead before pconv_k overwrites it):
    //   [contrib bf16 51.2MB][adj 25.6MB][counts 0.8MB] = 77.6MB < 102.4MB
    __hip_bfloat16* contrib = (__hip_bfloat16*)d_out;
    int* adj    = (int*)((char*)d_out + (size_t)NFACE * CIN * 2);
    int* counts = (int*)((char*)adj + (size_t)NVERT * CAP * 4);

    hipMemsetAsync(stats, 0, 8192, stream);
    hipMemsetAsync(counts, 0, (size_t)NVERT * sizeof(int), stream);

    contrib_adj_k<<<NFACE / 16, 256, 0, stream>>>(inputs, filt, face, sw,
                                                  contrib, counts, adj);
    gather2_k<<<NVERT / 4, 256, 0, stream>>>(contrib, counts, adj, nf_count, agg);
    pconv_k<<<NVERT / BV, 256, 0, stream>>>(agg, vt_map, dw, bias, out, stats);
    bn_k<<<2048, 256, 0, stream>>>(out, stats, gamma, beta);
}

// Round 6
// 284.767 us; speedup vs baseline: 2.1622x; 1.1061x over previous
//
#include <hip/hip_runtime.h>
#include <hip/hip_bf16.h>

#define NFACE 400000
#define NVERT 200000
#define CIN 64
#define COUT 128
#define KF 27
#define CAP 32            // max faces/vertex (Poisson(6), observed max ~21)
#define BN_EPS 1e-5f
#define LST 56            // LDS row stride in shorts: 112B = 16B-aligned, bank-spread

typedef __attribute__((ext_vector_type(8))) short bf16x8;
typedef __attribute__((ext_vector_type(4))) float f32x4;

__device__ __forceinline__ short f2bf(float x) {
    __hip_bfloat16 h = __float2bfloat16(x);
    return *reinterpret_cast<short*>(&h);
}

// ---- Kernel 1: MFMA spatial mix + elementwise + adjacency (fused) --------
// 256 threads = 4 waves; 64 faces per block (16 per wave).
__global__ __launch_bounds__(256) void mix_k(
    const float* __restrict__ inputs,   // [NF,64]
    const float* __restrict__ filt,     // [NF,27]
    const int*   __restrict__ face,     // [NF,3]
    const float* __restrict__ sw,       // [27,64]
    __hip_bfloat16* __restrict__ contrib, // [NF,64]
    int* __restrict__ counts,           // [NV]
    int* __restrict__ adj)              // [NV,CAP]
{
    __shared__ short Af[64 * LST];      // filt tile bf16, K padded to 32
    __shared__ short Bs[64 * LST];      // sw^T bf16 [ch][k], K padded to 32
    const int t  = threadIdx.x;
    const int fb = blockIdx.x * 64;

    // stage sw^T : 1024 (ch,kpair) cells
#pragma unroll
    for (int j = 0; j < 4; ++j) {
        int idx = t + j * 256;          // 0..1023
        int ch = idx >> 4, k = (idx & 15) * 2;
        float v0 = (k     < KF) ? sw[k * 64 + ch]       : 0.f;
        float v1 = (k + 1 < KF) ? sw[(k + 1) * 64 + ch] : 0.f;
        Bs[ch * LST + k]     = f2bf(v0);
        Bs[ch * LST + k + 1] = f2bf(v1);
    }
    // stage filt tile
#pragma unroll
    for (int j = 0; j < 4; ++j) {
        int idx = t + j * 256;
        int fl = idx >> 4, k = (idx & 15) * 2;
        const float* fr = filt + (size_t)(fb + fl) * KF;
        float v0 = (k     < KF) ? fr[k]     : 0.f;
        float v1 = (k + 1 < KF) ? fr[k + 1] : 0.f;
        Af[fl * LST + k]     = f2bf(v0);
        Af[fl * LST + k + 1] = f2bf(v1);
    }
    // adjacency: one (face,corner) per thread for t<192
    if (t < 192) {
        int fl = t / 3, vi = t - fl * 3;
        int v = face[(size_t)(fb + fl) * 3 + vi];
        int s = atomicAdd(&counts[v], 1);
        if (s < CAP) adj[v * CAP + s] = fb + fl;
    }
    __syncthreads();

    const int lane = t & 63;
    const int wid  = t >> 6;
    const int r0   = wid * 16;          // wave's 16 faces within tile

    // A fragment: lane -> row = lane&15, k-chunk = (lane>>4)*8
    bf16x8 a = *(const bf16x8*)&Af[(r0 + (lane & 15)) * LST + (lane >> 4) * 8];

    f32x4 acc[4];
#pragma unroll
    for (int cb = 0; cb < 4; ++cb) {
        bf16x8 b = *(const bf16x8*)&Bs[(cb * 16 + (lane & 15)) * LST + (lane >> 4) * 8];
        acc[cb] = __builtin_amdgcn_mfma_f32_16x16x32_bf16(a, b, (f32x4){0.f, 0.f, 0.f, 0.f}, 0, 0, 0);
    }

    // elementwise inputs * W -> contrib (C layout: col=lane&15, row=(lane>>4)*4+i)
#pragma unroll
    for (int cb = 0; cb < 4; ++cb) {
#pragma unroll
        for (int i = 0; i < 4; ++i) {
            int f = fb + r0 + (lane >> 4) * 4 + i;
            int c = cb * 16 + (lane & 15);
            float v = inputs[(size_t)f * 64 + c] * acc[cb][i];
            contrib[(size_t)f * 64 + c] = __float2bfloat16(v);
        }
    }
}

// ---- Kernel 2: per-vertex gather with MLP --------------------------------
__global__ __launch_bounds__(256) void gather2_k(
    const __hip_bfloat16* __restrict__ contrib, // [NF,64]
    const int* __restrict__ counts,             // [NV]
    const int* __restrict__ adj,                // [NV,CAP]
    const int* __restrict__ nf_count,           // [NV]
    float* __restrict__ agg)                    // [NV,64] (already /denom)
{
    const int lane = threadIdx.x & 63;
    const int src  = blockIdx.x * 4 + (threadIdx.x >> 6);
    int n = counts[src];
    n = n > CAP ? CAP : n;
    int adjv = (lane < n) ? adj[src * CAP + lane] : 0;

    float acc = 0.f;
    int j = 0;
    for (; j + 4 <= n; j += 4) {
        int f0 = __shfl(adjv, j + 0);
        int f1 = __shfl(adjv, j + 1);
        int f2 = __shfl(adjv, j + 2);
        int f3 = __shfl(adjv, j + 3);
        float a0 = __bfloat162float(contrib[(size_t)f0 * 64 + lane]);
        float a1 = __bfloat162float(contrib[(size_t)f1 * 64 + lane]);
        float a2 = __bfloat162float(contrib[(size_t)f2 * 64 + lane]);
        float a3 = __bfloat162float(contrib[(size_t)f3 * 64 + lane]);
        acc += (a0 + a1) + (a2 + a3);
    }
    for (; j < n; ++j) {
        int f = __shfl(adjv, j);
        acc += __bfloat162float(contrib[(size_t)f * 64 + lane]);
    }
    float denom = (float)max(nf_count[src], 1);
    agg[(size_t)src * 64 + lane] = acc / denom;
}

// ---- Kernel 3: pointwise conv + bias + ReLU + BN stats -------------------
#define BV 32   // vertices per block
__global__ __launch_bounds__(256) void pconv_k(
    const float* __restrict__ agg,       // [NV,64] (pre-divided)
    const int* __restrict__ vt_map,      // [NV] (int32)
    const float* __restrict__ dw,        // [64,128]
    const float* __restrict__ bias,      // [128]
    float* __restrict__ out,             // [NV,128]
    float* __restrict__ stats)           // [8][256]
{
    __shared__ float A[BV][64];
    const int c = threadIdx.x & 127;

    float wreg[64];
#pragma unroll
    for (int k = 0; k < 64; ++k) wreg[k] = dw[k * 128 + c];

    const int vbase = blockIdx.x * BV;
    for (int i = threadIdx.x; i < BV * 64; i += 256) {
        int vv = vbase + (i >> 6);
        int src = vt_map[vv];
        A[i >> 6][i & 63] = agg[(size_t)src * 64 + (i & 63)];
    }
    __syncthreads();

    const int half = threadIdx.x >> 7;
    float s = 0.f, s2 = 0.f;
    for (int vi = half * (BV / 2); vi < (half + 1) * (BV / 2); ++vi) {
        const float4* A4 = reinterpret_cast<const float4*>(&A[vi][0]);
        float acc = bias[c];
#pragma unroll
        for (int k4 = 0; k4 < 16; ++k4) {
            float4 a = A4[k4];
            acc += a.x * wreg[k4 * 4 + 0];
            acc += a.y * wreg[k4 * 4 + 1];
            acc += a.z * wreg[k4 * 4 + 2];
            acc += a.w * wreg[k4 * 4 + 3];
        }
        acc = fmaxf(acc, 0.f);
        out[(size_t)(vbase + vi) * 128 + c] = acc;
        s  += acc;
        s2 += acc * acc;
    }
    float* st = stats + (blockIdx.x & 7) * 256;
    atomicAdd(&st[c], s);
    atomicAdd(&st[128 + c], s2);
}

// ---- Kernel 4: BatchNorm finalize (in place on d_out) --------------------
__global__ __launch_bounds__(256) void bn_k(
    float* __restrict__ out,
    const float* __restrict__ stats,
    const float* __restrict__ gamma,
    const float* __restrict__ beta)
{
    __shared__ float sc[128], sh[128];
    if (threadIdx.x < 128) {
        int c = threadIdx.x;
        float s = 0.f, s2 = 0.f;
#pragma unroll
        for (int r = 0; r < 8; ++r) {
            s  += stats[r * 256 + c];
            s2 += stats[r * 256 + 128 + c];
        }
        float mean = s / (float)NVERT;
        float var  = s2 / (float)NVERT - mean * mean;
        float inv  = rsqrtf(var + BN_EPS) * gamma[c];
        sc[c] = inv;
        sh[c] = beta[c] - mean * inv;
    }
    __syncthreads();

    float4* o4 = reinterpret_cast<float4*>(out);
    size_t total4 = (size_t)NVERT * COUT / 4;
    for (size_t i = (size_t)blockIdx.x * 256 + threadIdx.x; i < total4;
         i += (size_t)gridDim.x * 256) {
        int c0 = (int)((i * 4) & 127);
        float4 v = o4[i];
        v.x = v.x * sc[c0 + 0] + sh[c0 + 0];
        v.y = v.y * sc[c0 + 1] + sh[c0 + 1];
        v.z = v.z * sc[c0 + 2] + sh[c0 + 2];
        v.w = v.w * sc[c0 + 3] + sh[c0 + 3];
        o4[i] = v;
    }
}

extern "C" void kernel_launch(void* const* d_in, const int* in_sizes, int n_in,
                              void* d_out, int out_size, void* d_ws, size_t ws_size,
                              hipStream_t stream) {
    const float* inputs   = (const float*)d_in[0];
    const float* filt     = (const float*)d_in[1];
    const int*   face     = (const int*)d_in[2];
    const int*   nf_count = (const int*)d_in[3];
    const int*   vt_map   = (const int*)d_in[4];
    const float* sw       = (const float*)d_in[5];
    const float* dw       = (const float*)d_in[6];
    const float* bias     = (const float*)d_in[7];
    const float* gamma    = (const float*)d_in[8];
    const float* beta     = (const float*)d_in[9];
    float* out = (float*)d_out;

    // ws: [stats 8KB][agg 51.2MB]
    float* stats = (float*)d_ws;
    float* agg   = (float*)((char*)d_ws + 8192);

    // staged inside d_out (dead before pconv_k overwrites it):
    //   [contrib bf16 51.2MB][adj 25.6MB][counts 0.8MB] = 77.6MB < 102.4MB
    __hip_bfloat16* contrib = (__hip_bfloat16*)d_out;
    int* adj    = (int*)((char*)d_out + (size_t)NFACE * CIN * 2);
    int* counts = (int*)((char*)adj + (size_t)NVERT * CAP * 4);

    hipMemsetAsync(stats, 0, 8192, stream);
    hipMemsetAsync(counts, 0, (size_t)NVERT * sizeof(int), stream);

    mix_k<<<NFACE / 64, 256, 0, stream>>>(inputs, filt, face, sw,
                                          contrib, counts, adj);
    gather2_k<<<NVERT / 4, 256, 0, stream>>>(contrib, counts, adj, nf_count, agg);
    pconv_k<<<NVERT / BV, 256, 0, stream>>>(agg, vt_map, dw, bias, out, stats);
    bn_k<<<2048, 256, 0, stream>>>(out, stats, gamma, beta);
}